// Round 8
// baseline (17.627 us; speedup 1.0000x reference)
//
#include <hip/hip_runtime.h>
#include <math.h>

#define HH 128
#define WW 128
#define TT 8
#define NG 1024
#define PP (HH * WW * TT)      // 131072 pixels
#define YP 64                  // y-pairs (rows 2y, 2y+1)

// ws layout (float units):
#define REC_OFF    0                       // NG*16 floats: G records
#define SLIST_OFF  (NG * 16)               // YP*NG ints: survivor lists
#define SCOUNT_OFF (SLIST_OFF + YP * NG)   // YP ints: survivor counts
#define WS_FLOATS  (SCOUNT_OFF + YP)

// tanh via exp2 (used by fallback only)
__device__ __forceinline__ float fast_tanh(float x) {
    float e = __builtin_amdgcn_exp2f(x * 2.885390081777926814f);
    return 1.f - 2.f * __builtin_amdgcn_rcpf(e + 1.f);
}

// ---------------------------------------------------------------------------
// Prep kernel, grid = YP + NG/128 = 72 blocks.
// Blocks [0,64): survivor list for y-pair b. Band test (t-independent,
//   conservative): min over continuous (x,t) of sigma at fixed y is
//   dy^2/(2*Sigma_yy); Sigma_yy = c1^2 + c3^2 from raw cholesky.
//   keep iff dmin^2 < 32*Sigma_yy (sigma<16). Index-ordered compaction.
// Blocks [64,72): full per-gaussian setup -> G record (float4 x4):
//   {G0,G1,G2,G3} {G4,G5,G6,G7} {G8,G9,0,0} {fc0,fc1,fc2,0}
// ---------------------------------------------------------------------------
__global__ __launch_bounds__(256) void gv_prep(
    const float* __restrict__ xyz,
    const float* __restrict__ chol,
    const float* __restrict__ feat,
    const float* __restrict__ opac,
    float* __restrict__ ws)
{
    const int bid = blockIdx.x;
    const int tid = threadIdx.x;

    if (bid < YP) {
        __shared__ int cnt_lds[4];
        int* slist = (int*)(ws + SLIST_OFF) + bid * NG;
        int* scount = (int*)(ws + SCOUNT_OFF);
        const int lane = tid & 63;
        const int wv = tid >> 6;
        const float y0f = (float)(2 * bid);

        int S_run = 0;
        for (int it = 0; it < NG / 256; ++it) {
            const int n = it * 256 + tid;
            float vy = xyz[n * 3 + 1];
            float c1 = chol[n * 6 + 1];
            float c3 = chol[n * 6 + 3] + 0.5f;
            float my = fmaf(tanhf(vy), 64.f, 63.5f);   // 0.5*((tanh+1)*128-1)
            float syy = fmaf(c1, c1, c3 * c3);         // Sigma_yy
            float d0 = my - y0f;
            float d1 = d0 - 1.f;
            float dmin = fminf(fabsf(d0), fabsf(d1));
            bool keep = dmin * dmin < 32.f * syy;

            unsigned long long mask = __ballot(keep);
            if (lane == 0) cnt_lds[wv] = (int)__popcll(mask);
            __syncthreads();
            int base = S_run;
            for (int w = 0; w < wv; ++w) base += cnt_lds[w];
            int tot = cnt_lds[0] + cnt_lds[1] + cnt_lds[2] + cnt_lds[3];
            if (keep) {
                int pos = __builtin_amdgcn_mbcnt_hi(
                              (unsigned)(mask >> 32),
                              __builtin_amdgcn_mbcnt_lo((unsigned)mask, 0));
                slist[base + pos] = n;
            }
            S_run += tot;
            __syncthreads();
        }
        if (tid == 0) scount[bid] = S_run;
    } else {
        const int n = (bid - YP) * 128 + tid;
        if (tid >= 128) return;

        float vx = xyz[n * 3 + 0], vy = xyz[n * 3 + 1], vt = xyz[n * 3 + 2];
        float mx = 0.5f * ((tanhf(vx) + 1.f) * (float)WW - 1.f);
        float my = 0.5f * ((tanhf(vy) + 1.f) * (float)HH - 1.f);
        float mt = 0.5f * ((tanhf(vt) + 1.f) * (float)TT - 1.f);

        float c0 = chol[n * 6 + 0] + 0.5f;
        float c1 = chol[n * 6 + 1];
        float c2 = chol[n * 6 + 2] + 0.5f;
        float c3 = chol[n * 6 + 3] + 0.5f;
        float c4 = chol[n * 6 + 4];
        float c5 = chol[n * 6 + 5] + 0.5f;

        float a  = c0 * c0;
        float b  = c0 * c1;
        float cc = c0 * c2;
        float d  = c1 * c1 + c3 * c3;
        float e  = c1 * c2 + c3 * c4;
        float f  = c2 * c2 + c4 * c4 + c5 * c5;

        float A00 = d * f - e * e;
        float A01 = cc * e - b * f;
        float A02 = b * e - cc * d;
        float A11 = a * f - cc * cc;
        float A12 = b * cc - a * e;
        float A22 = a * d - b * b;
        float det = a * A00 + b * A01 + cc * A02;
        float rdet = 1.f / det;
        float Q00 = A00 * rdet, Q01 = A01 * rdet, Q02 = A02 * rdet;
        float Q11 = A11 * rdet, Q12 = A12 * rdet, Q22 = A22 * rdet;

        float qmx = Q00 * mx + Q01 * my + Q02 * mt;
        float qmy = Q01 * mx + Q11 * my + Q12 * mt;
        float qmt = Q02 * mx + Q12 * my + Q22 * mt;
        float cst = 0.5f * (mx * qmx + my * qmy + mt * qmt);

        float op = opac[n];
        float4* r4 = (float4*)(ws + REC_OFF);
        r4[n * 4 + 0] = (float4){0.5f * Q00, 0.5f * Q11, 0.5f * Q22, Q01};
        r4[n * 4 + 1] = (float4){Q02, Q12, -qmx, -qmy};
        r4[n * 4 + 2] = (float4){-qmt, cst, 0.f, 0.f};
        r4[n * 4 + 3] = (float4){op * feat[n * 3 + 0], op * feat[n * 3 + 1],
                                 op * feat[n * 3 + 2], 0.f};
    }
}

// ---------------------------------------------------------------------------
// Main kernel, grid = 512: block b -> y-pair (b & 63) at time (b >> 6).
// 256 threads = 4 waves; waves {0,1} row 0 (x halves), {2,3} row 1; 1 px/lane.
// Stage B: fold (t, y) into per-row quadratic coeffs for the S survivors.
// Stage C: blend survivors; clip; write out [3][H][W][T].
// ---------------------------------------------------------------------------
__global__ __launch_bounds__(256) void gv_main(
    const float* __restrict__ ws,
    float* __restrict__ out)
{
    __shared__ __align__(16) float recs[NG * 8];   // worst-case 32 KB

    const int tid = threadIdx.x;
    const int lane = tid & 63;
    const int wv = tid >> 6;
    const int yp = blockIdx.x & 63;
    const int t  = blockIdx.x >> 6;
    const float y0f = (float)(2 * yp);
    const float tf  = (float)t;
    const float kneg = -1.44269504088896340736f;   // -log2(e)

    const int* slist = (const int*)(ws + SLIST_OFF) + yp * NG;
    const int S = ((const int*)(ws + SCOUNT_OFF))[yp];
    const float4* g4 = (const float4*)(ws + REC_OFF);

    // ---- stage B: fold (t,y) for survivors ----
    for (int j = tid; j < S; j += 256) {
        const int n = slist[j];
        float4 ra = g4[n * 4 + 0];   // G0 G1 G2 G3
        float4 rb = g4[n * 4 + 1];   // G4 G5 G6 G7
        float4 rc = g4[n * 4 + 2];   // G8 G9 - -
        float4 rd = g4[n * 4 + 3];   // fc0 fc1 fc2 -

        float u  = fmaf(rb.x, tf, rb.z);
        float v  = fmaf(rb.y, tf, rb.w);
        float w0 = fmaf(fmaf(ra.z, tf, rc.x), tf, rc.y);
        float B0 = fmaf(ra.w, y0f, u);
        float C0 = fmaf(fmaf(ra.y, y0f, v), y0f, w0);
        float y1f = y0f + 1.f;
        float B1 = fmaf(ra.w, y1f, u);
        float C1 = fmaf(fmaf(ra.y, y1f, v), y1f, w0);

        float4* l4 = (float4*)recs;
        l4[j * 2 + 0] = (float4){kneg * ra.x, rd.x, rd.y, rd.z};
        l4[j * 2 + 1] = (float4){kneg * B0, kneg * C0, kneg * B1, kneg * C1};
    }
    __syncthreads();

    // ---- stage C: blend ----
    const int rowi = wv >> 1;
    const int x = (wv & 1) * 64 + lane;
    const float xf = (float)x;
    float a0 = 0.f, a1 = 0.f, a2 = 0.f;
    const float4* lds4 = (const float4*)recs;

#pragma unroll 4
    for (int m = 0; m < S; ++m) {
        float4 af = lds4[m * 2];                                 // {A,f0,f1,f2}
        float2 bc = *(const float2*)&recs[m * 8 + 4 + 2 * rowi]; // {B,C} my row
        float s = fmaf(fmaf(af.x, xf, bc.x), xf, bc.y);
        float w = __builtin_amdgcn_exp2f(s);
        a0 = fmaf(w, af.y, a0);
        a1 = fmaf(w, af.z, a1);
        a2 = fmaf(w, af.w, a2);
    }

    a0 = fminf(fmaxf(a0, 0.f), 1.f);
    a1 = fminf(fmaxf(a1, 0.f), 1.f);
    a2 = fminf(fmaxf(a2, 0.f), 1.f);

    const int y = 2 * yp + rowi;
    const int base_o = (y * WW + x) * TT + t;
    out[base_o] = a0;
    out[base_o + PP] = a1;
    out[base_o + 2 * PP] = a2;
}

// ---------------------------------------------------------------------------
// Fallback: R7's single fused kernel (no workspace needed).
// ---------------------------------------------------------------------------
__global__ __launch_bounds__(256) void gv_fused(
    const float* __restrict__ xyz,
    const float* __restrict__ chol,
    const float* __restrict__ feat,
    const float* __restrict__ opac,
    float* __restrict__ out)
{
    __shared__ __align__(16) float recs[NG * 8];
    __shared__ int sidx[NG];
    __shared__ int cnt_lds[4];

    const int tid = threadIdx.x;
    const int lane = tid & 63;
    const int wv = tid >> 6;
    const int r0 = blockIdx.x * 2;
    const float y0f = (float)(r0 & 127);
    const float tf  = (float)(r0 >> 7);
    const float kneg = -1.44269504088896340736f;

    int S_run = 0;
    for (int it = 0; it < NG / 256; ++it) {
        const int n = it * 256 + tid;
        float vy = xyz[n * 3 + 1];
        float c1 = chol[n * 6 + 1];
        float c3 = chol[n * 6 + 3] + 0.5f;
        float my = fmaf(fast_tanh(vy), 64.f, 63.5f);
        float syy = fmaf(c1, c1, c3 * c3);
        float d0 = my - y0f;
        float d1 = d0 - 1.f;
        float dmin = fminf(fabsf(d0), fabsf(d1));
        bool keep = dmin * dmin < 32.f * syy;

        unsigned long long mask = __ballot(keep);
        if (lane == 0) cnt_lds[wv] = (int)__popcll(mask);
        __syncthreads();
        int base = S_run;
        for (int w = 0; w < wv; ++w) base += cnt_lds[w];
        int tot = cnt_lds[0] + cnt_lds[1] + cnt_lds[2] + cnt_lds[3];
        if (keep) {
            int pos = __builtin_amdgcn_mbcnt_hi(
                          (unsigned)(mask >> 32),
                          __builtin_amdgcn_mbcnt_lo((unsigned)mask, 0));
            sidx[base + pos] = n;
        }
        S_run += tot;
        __syncthreads();
    }
    const int S = S_run;

    for (int j = tid; j < S; j += 256) {
        const int n = sidx[j];
        float vx = xyz[n * 3 + 0], vy = xyz[n * 3 + 1], vt = xyz[n * 3 + 2];
        float mx = 0.5f * ((fast_tanh(vx) + 1.f) * (float)WW - 1.f);
        float my = 0.5f * ((fast_tanh(vy) + 1.f) * (float)HH - 1.f);
        float mt = 0.5f * ((fast_tanh(vt) + 1.f) * (float)TT - 1.f);
        float c0 = chol[n * 6 + 0] + 0.5f;
        float c1 = chol[n * 6 + 1];
        float c2 = chol[n * 6 + 2] + 0.5f;
        float c3 = chol[n * 6 + 3] + 0.5f;
        float c4 = chol[n * 6 + 4];
        float c5 = chol[n * 6 + 5] + 0.5f;
        float a  = c0 * c0, b = c0 * c1, cc = c0 * c2;
        float d  = c1 * c1 + c3 * c3;
        float e  = c1 * c2 + c3 * c4;
        float f  = c2 * c2 + c4 * c4 + c5 * c5;
        float A00 = d * f - e * e, A01 = cc * e - b * f, A02 = b * e - cc * d;
        float A11 = a * f - cc * cc, A12 = b * cc - a * e, A22 = a * d - b * b;
        float det = a * A00 + b * A01 + cc * A02;
        float rdet = 1.f / det;
        float Q00 = A00 * rdet, Q01 = A01 * rdet, Q02 = A02 * rdet;
        float Q11 = A11 * rdet, Q12 = A12 * rdet, Q22 = A22 * rdet;
        float qmx = Q00 * mx + Q01 * my + Q02 * mt;
        float qmy = Q01 * mx + Q11 * my + Q12 * mt;
        float qmt = Q02 * mx + Q12 * my + Q22 * mt;
        float cst = 0.5f * (mx * qmx + my * qmy + mt * qmt);
        float G0 = 0.5f * Q00, G1 = 0.5f * Q11, G2 = 0.5f * Q22;
        float G3 = Q01, G4 = Q02, G5 = Q12;
        float G6 = -qmx, G7 = -qmy, G8 = -qmt, G9 = cst;

        float u  = fmaf(G4, tf, G6);
        float v  = fmaf(G5, tf, G7);
        float w0 = fmaf(fmaf(G2, tf, G8), tf, G9);
        float B0 = fmaf(G3, y0f, u);
        float C0 = fmaf(fmaf(G1, y0f, v), y0f, w0);
        float y1f = y0f + 1.f;
        float B1 = fmaf(G3, y1f, u);
        float C1 = fmaf(fmaf(G1, y1f, v), y1f, w0);

        float op = opac[n];
        float4* l4 = (float4*)recs;
        l4[j * 2 + 0] = (float4){kneg * G0, op * feat[n * 3 + 0],
                                 op * feat[n * 3 + 1], op * feat[n * 3 + 2]};
        l4[j * 2 + 1] = (float4){kneg * B0, kneg * C0, kneg * B1, kneg * C1};
    }
    __syncthreads();

    const int rowi = wv >> 1;
    const int x = (wv & 1) * 64 + lane;
    const float xf = (float)x;
    float a0 = 0.f, a1 = 0.f, a2 = 0.f;
    const float4* lds4 = (const float4*)recs;

#pragma unroll 4
    for (int m = 0; m < S; ++m) {
        float4 af = lds4[m * 2];
        float2 bc = *(const float2*)&recs[m * 8 + 4 + 2 * rowi];
        float s = fmaf(fmaf(af.x, xf, bc.x), xf, bc.y);
        float w = __builtin_amdgcn_exp2f(s);
        a0 = fmaf(w, af.y, a0);
        a1 = fmaf(w, af.z, a1);
        a2 = fmaf(w, af.w, a2);
    }

    a0 = fminf(fmaxf(a0, 0.f), 1.f);
    a1 = fminf(fmaxf(a1, 0.f), 1.f);
    a2 = fminf(fmaxf(a2, 0.f), 1.f);

    const int r = r0 + rowi;
    const int y = r & 127, t = r >> 7;
    const int base_o = (y * WW + x) * TT + t;
    out[base_o] = a0;
    out[base_o + PP] = a1;
    out[base_o + 2 * PP] = a2;
}

extern "C" void kernel_launch(void* const* d_in, const int* in_sizes, int n_in,
                              void* d_out, int out_size, void* d_ws, size_t ws_size,
                              hipStream_t stream) {
    const float* xyz  = (const float*)d_in[0];
    const float* chol = (const float*)d_in[1];
    const float* feat = (const float*)d_in[2];
    const float* opac = (const float*)d_in[3];
    float* out = (float*)d_out;
    float* ws  = (float*)d_ws;

    if (ws_size >= (size_t)WS_FLOATS * sizeof(float)) {
        gv_prep<<<YP + NG / 128, 256, 0, stream>>>(xyz, chol, feat, opac, ws);
        gv_main<<<YP * TT, 256, 0, stream>>>(ws, out);
    } else {
        gv_fused<<<(TT * HH) / 2, 256, 0, stream>>>(xyz, chol, feat, opac, out);
    }
}

// Round 9
// 13.288 us; speedup vs baseline: 1.3265x; 1.3265x over previous
//
#include <hip/hip_runtime.h>
#include <math.h>

#define HH 128
#define WW 128
#define TT 8
#define NG 1024
#define PP (HH * WW * TT)      // 131072 pixels

// tanh via exp2: tanh(x) = 1 - 2/(exp2(2*log2e*x)+1). ~1e-7 rel err, deterministic.
__device__ __forceinline__ float fast_tanh(float x) {
    float e = __builtin_amdgcn_exp2f(x * 2.885390081777926814f);
    return 1.f - 2.f * __builtin_amdgcn_rcpf(e + 1.f);
}

// ---------------------------------------------------------------------------
// Single fused kernel. Block = 256 threads = 4 waves; covers 2 rows
// (r = t*128 + y): waves {0,1} -> row 0 (x-halves 0/1), waves {2,3} -> row 1.
// One pixel per lane.
//
// Stage A (BARRIER-FREE): wave w owns gaussian segment [256w, 256w+256),
//   4 ballot rounds of 64 with a wave-local running count (ballot/mbcnt are
//   wave-synchronous). Cheap conservative cull: min over continuous (x,t) of
//   sigma at fixed y is dy^2/(2*Sigma_yy); Sigma_yy = c1^2+c3^2 from raw
//   cholesky; keep iff dmin^2 < 32*Sigma_yy (sigma<16, e^-16 ~ 1e-7).
//   Survivor indices -> sidx[256w + pos]. ONE barrier at the end.
// Stage B: compact j in [0,S): map j->segment (3 compares), full setup
//   (tanh means, L L^T, 3x3 inverse, fold t and the 2 rows) -> recs[j]
//   packed contiguous, ascending gaussian index (bit-identical sum order).
// Stage C: blend S survivors: Horner + exp2 + 3 blend FMA; clip; write out.
// ---------------------------------------------------------------------------
__global__ __launch_bounds__(256) void gv_fused(
    const float* __restrict__ xyz,
    const float* __restrict__ chol,
    const float* __restrict__ feat,
    const float* __restrict__ opac,
    float* __restrict__ out)
{
    __shared__ __align__(16) float recs[NG * 8];   // 32 KB survivor records
    __shared__ int sidx[NG];                       // 4 KB survivor indices
    __shared__ int cnt_lds[4];

    const int tid = threadIdx.x;
    const int lane = tid & 63;
    const int wv = tid >> 6;
    const int r0 = blockIdx.x * 2;                 // rows r0, r0+1 (same t)
    const float y0f = (float)(r0 & 127);
    const float tf  = (float)(r0 >> 7);
    const float kneg = -1.44269504088896340736f;   // -log2(e)

    // ---- stage A: wave-local barrier-free cull over segment [256w,256w+256) ----
    {
        int cnt = 0;
#pragma unroll
        for (int it = 0; it < 4; ++it) {
            const int n = wv * 256 + it * 64 + lane;
            float vy = xyz[n * 3 + 1];
            float c1 = chol[n * 6 + 1];
            float c3 = chol[n * 6 + 3] + 0.5f;
            float my = fmaf(fast_tanh(vy), 64.f, 63.5f);   // 0.5*((tanh+1)*128-1)
            float syy = fmaf(c1, c1, c3 * c3);             // Sigma_yy
            float d0 = my - y0f;
            float d1 = d0 - 1.f;
            float dmin = fminf(fabsf(d0), fabsf(d1));
            bool keep = dmin * dmin < 32.f * syy;

            unsigned long long mask = __ballot(keep);
            if (keep) {
                int pos = __builtin_amdgcn_mbcnt_hi(
                              (unsigned)(mask >> 32),
                              __builtin_amdgcn_mbcnt_lo((unsigned)mask, 0));
                sidx[wv * 256 + cnt + pos] = n;
            }
            cnt += (int)__popcll(mask);
        }
        if (lane == 0) cnt_lds[wv] = cnt;
    }
    __syncthreads();

    const int c0s = cnt_lds[0], c1s = cnt_lds[1];
    const int c2s = cnt_lds[2], c3s = cnt_lds[3];
    const int off1 = c0s, off2 = c0s + c1s, off3 = c0s + c1s + c2s;
    const int S = off3 + c3s;

    // ---- stage B: full setup for survivors, packed ascending ----
    for (int j = tid; j < S; j += 256) {
        int seg = (j >= off1) + (j >= off2) + (j >= off3);
        int base = seg == 0 ? 0 : (seg == 1 ? off1 : (seg == 2 ? off2 : off3));
        const int n = sidx[seg * 256 + (j - base)];

        float vx = xyz[n * 3 + 0], vy = xyz[n * 3 + 1], vt = xyz[n * 3 + 2];
        float mx = 0.5f * ((fast_tanh(vx) + 1.f) * (float)WW - 1.f);
        float my = 0.5f * ((fast_tanh(vy) + 1.f) * (float)HH - 1.f);
        float mt = 0.5f * ((fast_tanh(vt) + 1.f) * (float)TT - 1.f);

        float c0 = chol[n * 6 + 0] + 0.5f;
        float c1 = chol[n * 6 + 1];
        float c2 = chol[n * 6 + 2] + 0.5f;
        float c3 = chol[n * 6 + 3] + 0.5f;
        float c4 = chol[n * 6 + 4];
        float c5 = chol[n * 6 + 5] + 0.5f;

        // Sigma = L L^T
        float a  = c0 * c0;
        float b  = c0 * c1;
        float cc = c0 * c2;
        float d  = c1 * c1 + c3 * c3;
        float e  = c1 * c2 + c3 * c4;
        float f  = c2 * c2 + c4 * c4 + c5 * c5;

        // symmetric 3x3 inverse via adjugate
        float A00 = d * f - e * e;
        float A01 = cc * e - b * f;
        float A02 = b * e - cc * d;
        float A11 = a * f - cc * cc;
        float A12 = b * cc - a * e;
        float A22 = a * d - b * b;
        float det = a * A00 + b * A01 + cc * A02;
        float rdet = 1.f / det;
        float Q00 = A00 * rdet, Q01 = A01 * rdet, Q02 = A02 * rdet;
        float Q11 = A11 * rdet, Q12 = A12 * rdet, Q22 = A22 * rdet;

        float qmx = Q00 * mx + Q01 * my + Q02 * mt;
        float qmy = Q01 * mx + Q11 * my + Q12 * mt;
        float qmt = Q02 * mx + Q12 * my + Q22 * mt;
        float cst = 0.5f * (mx * qmx + my * qmy + mt * qmt);

        float G0 = 0.5f * Q00, G1 = 0.5f * Q11, G2 = 0.5f * Q22;
        float G3 = Q01, G4 = Q02, G5 = Q12;
        float G6 = -qmx, G7 = -qmy, G8 = -qmt, G9 = cst;

        // fold t (block-constant), then the block's two rows
        float u  = fmaf(G4, tf, G6);
        float v  = fmaf(G5, tf, G7);
        float w0 = fmaf(fmaf(G2, tf, G8), tf, G9);
        float B0 = fmaf(G3, y0f, u);
        float C0 = fmaf(fmaf(G1, y0f, v), y0f, w0);
        float y1f = y0f + 1.f;
        float B1 = fmaf(G3, y1f, u);
        float C1 = fmaf(fmaf(G1, y1f, v), y1f, w0);

        float op = opac[n];
        float4* l4 = (float4*)recs;
        l4[j * 2 + 0] = (float4){kneg * G0, op * feat[n * 3 + 0],
                                 op * feat[n * 3 + 1], op * feat[n * 3 + 2]};
        l4[j * 2 + 1] = (float4){kneg * B0, kneg * C0, kneg * B1, kneg * C1};
    }
    __syncthreads();

    // ---- stage C: blend S survivors, 1 px per lane ----
    const int rowi = wv >> 1;
    const int x = (wv & 1) * 64 + lane;
    const float xf = (float)x;
    float a0 = 0.f, a1 = 0.f, a2 = 0.f;
    const float4* lds4 = (const float4*)recs;

#pragma unroll 4
    for (int m = 0; m < S; ++m) {
        float4 af = lds4[m * 2];                                 // {A,f0,f1,f2}
        float2 bc = *(const float2*)&recs[m * 8 + 4 + 2 * rowi]; // {B,C} my row
        float s = fmaf(fmaf(af.x, xf, bc.x), xf, bc.y);
        float w = __builtin_amdgcn_exp2f(s);
        a0 = fmaf(w, af.y, a0);
        a1 = fmaf(w, af.z, a1);
        a2 = fmaf(w, af.w, a2);
    }

    a0 = fminf(fmaxf(a0, 0.f), 1.f);
    a1 = fminf(fmaxf(a1, 0.f), 1.f);
    a2 = fminf(fmaxf(a2, 0.f), 1.f);

    // layout: [3][H][W][T], base = (y*W + x)*T + t
    const int r = r0 + rowi;
    const int y = r & 127, t = r >> 7;
    const int base_o = (y * WW + x) * TT + t;
    out[base_o] = a0;
    out[base_o + PP] = a1;
    out[base_o + 2 * PP] = a2;
}

extern "C" void kernel_launch(void* const* d_in, const int* in_sizes, int n_in,
                              void* d_out, int out_size, void* d_ws, size_t ws_size,
                              hipStream_t stream) {
    const float* xyz  = (const float*)d_in[0];
    const float* chol = (const float*)d_in[1];
    const float* feat = (const float*)d_in[2];
    const float* opac = (const float*)d_in[3];
    float* out = (float*)d_out;

    const int blocks = (TT * HH) / 2;        // 512 blocks, 2 rows each
    gv_fused<<<blocks, 256, 0, stream>>>(xyz, chol, feat, opac, out);
}

// Round 10
// 12.505 us; speedup vs baseline: 1.4096x; 1.0626x over previous
//
#include <hip/hip_runtime.h>
#include <math.h>

#define HH 128
#define WW 128
#define TT 8
#define NG 1024
#define PP (HH * WW * TT)      // 131072 pixels
#define GH 512                 // gaussians per half

// tanh via exp2: tanh(x) = 1 - 2/(exp2(2*log2e*x)+1). ~1e-7 rel err, deterministic.
__device__ __forceinline__ float fast_tanh(float x) {
    float e = __builtin_amdgcn_exp2f(x * 2.885390081777926814f);
    return 1.f - 2.f * __builtin_amdgcn_rcpf(e + 1.f);
}

// ---------------------------------------------------------------------------
// Single fused kernel. Block = 512 threads = 8 waves; covers 2 rows
// (r = t*128 + y). Gaussians split in two halves to double wave-parallelism:
//   wave w: half h = w>>2 owns gaussians [512h, 512h+512);
//           combo c = w&3: row c>>1, x-half c&1. One pixel per lane.
// Stage A (barrier-free): within half h, wave-segment i = w&3 scans
//   [512h + 128i, +128) in 2 ballot rounds, wave-local running count.
//   Cheap conservative cull: min over continuous (x,t) of sigma at fixed y
//   is dy^2/(2*Sigma_yy); Sigma_yy = c1^2+c3^2 from raw cholesky;
//   keep iff dmin^2 < 32*Sigma_yy (sigma<16, e^-16 ~ 1.1e-7).
// Stage B: per half, its 256 threads do full setup for the S_h survivors
//   (packed ascending gaussian index) -> recs[h].
// Stage C: each wave blends its half's survivors for its 64 px; half-1
//   waves park partials in LDS; half-0 waves add (fixed order lo+hi),
//   clip, write out [3][H][W][T].
// ---------------------------------------------------------------------------
__global__ __launch_bounds__(512) void gv_fused(
    const float* __restrict__ xyz,
    const float* __restrict__ chol,
    const float* __restrict__ feat,
    const float* __restrict__ opac,
    float* __restrict__ out)
{
    __shared__ __align__(16) float recs[2][GH * 8];  // 32 KB survivor records
    __shared__ int sidx[2][GH];                      // 4 KB survivor indices
    __shared__ int cnt_lds[8];
    __shared__ float pbuf[4][3][64];                 // 3 KB half-1 partials

    const int tid = threadIdx.x;
    const int lane = tid & 63;
    const int wv = tid >> 6;                 // 0..7
    const int h = wv >> 2;                   // gaussian half
    const int seg_i = wv & 3;                // 128-gaussian segment in half
    const int r0 = blockIdx.x * 2;           // rows r0, r0+1 (same t)
    const float y0f = (float)(r0 & 127);
    const float tf  = (float)(r0 >> 7);
    const float kneg = -1.44269504088896340736f;   // -log2(e)

    // ---- stage A: barrier-free cull, wave-local compaction ----
    {
        int cnt = 0;
#pragma unroll
        for (int it = 0; it < 2; ++it) {
            const int n = h * GH + seg_i * 128 + it * 64 + lane;
            float vy = xyz[n * 3 + 1];
            float c1 = chol[n * 6 + 1];
            float c3 = chol[n * 6 + 3] + 0.5f;
            float my = fmaf(fast_tanh(vy), 64.f, 63.5f);   // 0.5*((tanh+1)*128-1)
            float syy = fmaf(c1, c1, c3 * c3);             // Sigma_yy
            float d0 = my - y0f;
            float d1 = d0 - 1.f;
            float dmin = fminf(fabsf(d0), fabsf(d1));
            bool keep = dmin * dmin < 32.f * syy;

            unsigned long long mask = __ballot(keep);
            if (keep) {
                int pos = __builtin_amdgcn_mbcnt_hi(
                              (unsigned)(mask >> 32),
                              __builtin_amdgcn_mbcnt_lo((unsigned)mask, 0));
                sidx[h][seg_i * 128 + cnt + pos] = n;
            }
            cnt += (int)__popcll(mask);
        }
        if (lane == 0) cnt_lds[wv] = cnt;
    }
    __syncthreads();

    const int b0 = cnt_lds[h * 4 + 0], b1 = cnt_lds[h * 4 + 1];
    const int b2 = cnt_lds[h * 4 + 2], b3 = cnt_lds[h * 4 + 3];
    const int off1 = b0, off2 = b0 + b1, off3 = b0 + b1 + b2;
    const int S = off3 + b3;                 // survivors in my half

    // ---- stage B: full setup for my half's survivors, packed ascending ----
    const int tg = tid & 255;                // thread index within half-group
    for (int j = tg; j < S; j += 256) {
        int seg = (j >= off1) + (j >= off2) + (j >= off3);
        int base = seg == 0 ? 0 : (seg == 1 ? off1 : (seg == 2 ? off2 : off3));
        const int n = sidx[h][seg * 128 + (j - base)];

        float vx = xyz[n * 3 + 0], vy = xyz[n * 3 + 1], vt = xyz[n * 3 + 2];
        float mx = 0.5f * ((fast_tanh(vx) + 1.f) * (float)WW - 1.f);
        float my = 0.5f * ((fast_tanh(vy) + 1.f) * (float)HH - 1.f);
        float mt = 0.5f * ((fast_tanh(vt) + 1.f) * (float)TT - 1.f);

        float c0 = chol[n * 6 + 0] + 0.5f;
        float c1 = chol[n * 6 + 1];
        float c2 = chol[n * 6 + 2] + 0.5f;
        float c3 = chol[n * 6 + 3] + 0.5f;
        float c4 = chol[n * 6 + 4];
        float c5 = chol[n * 6 + 5] + 0.5f;

        // Sigma = L L^T
        float a  = c0 * c0;
        float b  = c0 * c1;
        float cc = c0 * c2;
        float d  = c1 * c1 + c3 * c3;
        float e  = c1 * c2 + c3 * c4;
        float f  = c2 * c2 + c4 * c4 + c5 * c5;

        // symmetric 3x3 inverse via adjugate
        float A00 = d * f - e * e;
        float A01 = cc * e - b * f;
        float A02 = b * e - cc * d;
        float A11 = a * f - cc * cc;
        float A12 = b * cc - a * e;
        float A22 = a * d - b * b;
        float det = a * A00 + b * A01 + cc * A02;
        float rdet = 1.f / det;
        float Q00 = A00 * rdet, Q01 = A01 * rdet, Q02 = A02 * rdet;
        float Q11 = A11 * rdet, Q12 = A12 * rdet, Q22 = A22 * rdet;

        float qmx = Q00 * mx + Q01 * my + Q02 * mt;
        float qmy = Q01 * mx + Q11 * my + Q12 * mt;
        float qmt = Q02 * mx + Q12 * my + Q22 * mt;
        float cst = 0.5f * (mx * qmx + my * qmy + mt * qmt);

        float G0 = 0.5f * Q00, G1 = 0.5f * Q11, G2 = 0.5f * Q22;
        float G3 = Q01, G4 = Q02, G5 = Q12;
        float G6 = -qmx, G7 = -qmy, G8 = -qmt, G9 = cst;

        // fold t (block-constant), then the block's two rows
        float u  = fmaf(G4, tf, G6);
        float v  = fmaf(G5, tf, G7);
        float w0 = fmaf(fmaf(G2, tf, G8), tf, G9);
        float B0 = fmaf(G3, y0f, u);
        float C0 = fmaf(fmaf(G1, y0f, v), y0f, w0);
        float y1f = y0f + 1.f;
        float B1 = fmaf(G3, y1f, u);
        float C1 = fmaf(fmaf(G1, y1f, v), y1f, w0);

        float op = opac[n];
        float4* l4 = (float4*)recs[h];
        l4[j * 2 + 0] = (float4){kneg * G0, op * feat[n * 3 + 0],
                                 op * feat[n * 3 + 1], op * feat[n * 3 + 2]};
        l4[j * 2 + 1] = (float4){kneg * B0, kneg * C0, kneg * B1, kneg * C1};
    }
    __syncthreads();

    // ---- stage C: blend my half's survivors for my 64 px ----
    const int combo = wv & 3;
    const int rowi = combo >> 1;
    const int x = (combo & 1) * 64 + lane;
    const float xf = (float)x;
    float a0 = 0.f, a1 = 0.f, a2 = 0.f;
    const float4* lds4 = (const float4*)recs[h];
    const float* recf = recs[h];

#pragma unroll 4
    for (int m = 0; m < S; ++m) {
        float4 af = lds4[m * 2];                                 // {A,f0,f1,f2}
        float2 bc = *(const float2*)&recf[m * 8 + 4 + 2 * rowi]; // {B,C} my row
        float s = fmaf(fmaf(af.x, xf, bc.x), xf, bc.y);
        float w = __builtin_amdgcn_exp2f(s);
        a0 = fmaf(w, af.y, a0);
        a1 = fmaf(w, af.z, a1);
        a2 = fmaf(w, af.w, a2);
    }

    // half-1 parks partials; half-0 merges (fixed order lo+hi), clips, stores
    if (h == 1) {
        pbuf[combo][0][lane] = a0;
        pbuf[combo][1][lane] = a1;
        pbuf[combo][2][lane] = a2;
    }
    __syncthreads();

    if (h == 0) {
        a0 += pbuf[combo][0][lane];
        a1 += pbuf[combo][1][lane];
        a2 += pbuf[combo][2][lane];

        a0 = fminf(fmaxf(a0, 0.f), 1.f);
        a1 = fminf(fmaxf(a1, 0.f), 1.f);
        a2 = fminf(fmaxf(a2, 0.f), 1.f);

        // layout: [3][H][W][T], base = (y*W + x)*T + t
        const int r = r0 + rowi;
        const int y = r & 127, t = r >> 7;
        const int base_o = (y * WW + x) * TT + t;
        out[base_o] = a0;
        out[base_o + PP] = a1;
        out[base_o + 2 * PP] = a2;
    }
}

extern "C" void kernel_launch(void* const* d_in, const int* in_sizes, int n_in,
                              void* d_out, int out_size, void* d_ws, size_t ws_size,
                              hipStream_t stream) {
    const float* xyz  = (const float*)d_in[0];
    const float* chol = (const float*)d_in[1];
    const float* feat = (const float*)d_in[2];
    const float* opac = (const float*)d_in[3];
    float* out = (float*)d_out;

    const int blocks = (TT * HH) / 2;        // 512 blocks, 2 rows each
    gv_fused<<<blocks, 512, 0, stream>>>(xyz, chol, feat, opac, out);
}